// Round 1
// baseline (369.738 us; speedup 1.0000x reference)
//
#include <hip/hip_runtime.h>
#include <stdint.h>

#define BATCH 8192
#define DIM 256

// Workspace layout (bytes):
//   wnorm : 5376 floats  @ 0        (levels concatenated: 256 | 1024 | 4096)
//   xnorm : 8192 floats  @ 21504
//   best  : 24576 u64    @ 54272    (level*8192 + row) packed (d2_bits<<32)|idx
#define WS_BEST_OFF 54272

__global__ __launch_bounds__(256) void norms_kernel(
    const float* __restrict__ x, const float* __restrict__ w1,
    const float* __restrict__ w2, const float* __restrict__ w3,
    float* __restrict__ wnorm, float* __restrict__ xnorm) {
  int task = blockIdx.x * 4 + (threadIdx.x >> 6);
  int lane = threadIdx.x & 63;
  const float* row;
  float* dst;
  if (task < 256)       { row = w1 + (size_t)task * DIM;          dst = wnorm + task; }
  else if (task < 1280) { row = w2 + (size_t)(task - 256) * DIM;  dst = wnorm + task; }
  else if (task < 5376) { row = w3 + (size_t)(task - 1280) * DIM; dst = wnorm + task; }
  else                  { row = x  + (size_t)(task - 5376) * DIM; dst = xnorm + (task - 5376); }
  float4 v = *(const float4*)(row + lane * 4);
  float s = v.x * v.x + v.y * v.y + v.z * v.z + v.w * v.w;
  #pragma unroll
  for (int o = 32; o > 0; o >>= 1) s += __shfl_xor(s, o);
  if (lane == 0) *dst = s;
}

// Fused GEMM(+argmin) over 64x64 tiles. grid.x = col-block (84: 4 | 16 | 64),
// grid.y = row-block (128). 256 threads, 4x4 register tile per thread.
__global__ __launch_bounds__(256) void dist_kernel(
    const float* __restrict__ x, const float* __restrict__ w1,
    const float* __restrict__ w2, const float* __restrict__ w3,
    const float* __restrict__ wnorm, const float* __restrict__ xnorm,
    unsigned long long* __restrict__ best) {
  __shared__ float As[16][68];  // [k][row]  (+4 pad: b128-aligned, 2-way max)
  __shared__ float Bs[16][68];  // [k][col]
  __shared__ unsigned long long red[64][16];

  int cb = blockIdx.x;
  const float* w; int j0, wnoff, boff;
  if (cb < 4)       { w = w1; j0 = cb * 64;        wnoff = 0;    boff = 0; }
  else if (cb < 20) { w = w2; j0 = (cb - 4) * 64;  wnoff = 256;  boff = 8192; }
  else              { w = w3; j0 = (cb - 20) * 64; wnoff = 1280; boff = 16384; }
  int r0 = blockIdx.y * 64;

  int t  = threadIdx.x;
  int tx = t & 15, ty = t >> 4;
  int sr = t >> 2;           // staging row/col 0..63
  int sk = (t & 3) * 4;      // staging k offset

  float acc[4][4];
  #pragma unroll
  for (int i = 0; i < 4; ++i)
    #pragma unroll
    for (int j = 0; j < 4; ++j) acc[i][j] = 0.0f;

  const float* aptr = x + (size_t)(r0 + sr) * DIM + sk;
  const float* bptr = w + (size_t)(j0 + sr) * DIM + sk;

  for (int k0 = 0; k0 < DIM; k0 += 16) {
    float4 av = *(const float4*)(aptr + k0);
    float4 bv = *(const float4*)(bptr + k0);
    __syncthreads();
    As[sk + 0][sr] = av.x; As[sk + 1][sr] = av.y;
    As[sk + 2][sr] = av.z; As[sk + 3][sr] = av.w;
    Bs[sk + 0][sr] = bv.x; Bs[sk + 1][sr] = bv.y;
    Bs[sk + 2][sr] = bv.z; Bs[sk + 3][sr] = bv.w;
    __syncthreads();
    #pragma unroll
    for (int k = 0; k < 16; ++k) {
      float4 af = *(const float4*)&As[k][ty * 4];
      float4 bf = *(const float4*)&Bs[k][tx * 4];
      float a[4] = {af.x, af.y, af.z, af.w};
      float b[4] = {bf.x, bf.y, bf.z, bf.w};
      #pragma unroll
      for (int i = 0; i < 4; ++i)
        #pragma unroll
        for (int j = 0; j < 4; ++j)
          acc[i][j] = fmaf(a[i], b[j], acc[i][j]);
    }
  }

  float xn[4], wn[4];
  #pragma unroll
  for (int i = 0; i < 4; ++i) xn[i] = xnorm[r0 + ty * 4 + i];
  #pragma unroll
  for (int j = 0; j < 4; ++j) wn[j] = wnorm[wnoff + j0 + tx * 4 + j];

  #pragma unroll
  for (int i = 0; i < 4; ++i) {
    float bd = 3.4e38f; int bj = 0;
    #pragma unroll
    for (int j = 0; j < 4; ++j) {
      float d2 = fmaxf(xn[i] + wn[j] - 2.0f * acc[i][j], 0.0f);
      if (d2 < bd) { bd = d2; bj = j; }   // strict < => lowest index on ties
    }
    unsigned long long p =
        ((unsigned long long)__float_as_uint(bd) << 32) |
        (unsigned)(j0 + tx * 4 + bj);
    red[ty * 4 + i][tx] = p;
  }
  __syncthreads();
  if (t < 64) {
    unsigned long long m = red[t][0];
    #pragma unroll
    for (int j = 1; j < 16; ++j) {
      unsigned long long p = red[t][j];
      m = (p < m) ? p : m;
    }
    atomicMin(&best[boff + r0 + t], m);
  }
}

// One wave per (level,row): coords + exact fp32 quantization error.
__global__ __launch_bounds__(256) void finalize_kernel(
    const float* __restrict__ x, const float* __restrict__ w1,
    const float* __restrict__ w2, const float* __restrict__ w3,
    const unsigned long long* __restrict__ best, float* __restrict__ out) {
  int task = blockIdx.x * 4 + (threadIdx.x >> 6);
  int lane = threadIdx.x & 63;
  int level = task >> 13;
  int row = task & 8191;
  const float* w; unsigned side;
  if (level == 0)      { w = w1; side = 16; }
  else if (level == 1) { w = w2; side = 32; }
  else                 { w = w3; side = 64; }
  unsigned idx = (unsigned)(best[level * 8192 + row] & 0xFFFFFFFFull);
  float4 xv = *(const float4*)(x + (size_t)row * DIM + lane * 4);
  float4 wv = *(const float4*)(w + (size_t)idx * DIM + lane * 4);
  float dx = xv.x - wv.x, dy = xv.y - wv.y, dz = xv.z - wv.z, dw = xv.w - wv.w;
  float s = dx * dx + dy * dy + dz * dz + dw * dw;
  #pragma unroll
  for (int o = 32; o > 0; o >>= 1) s += __shfl_xor(s, o);
  if (lane == 0) {
    out[level * 16384 + row * 2 + 0] = (float)(idx / side);
    out[level * 16384 + row * 2 + 1] = (float)(idx % side);
    out[49152 + level * 8192 + row] = sqrtf(s);
  }
}

extern "C" void kernel_launch(void* const* d_in, const int* in_sizes, int n_in,
                              void* d_out, int out_size, void* d_ws, size_t ws_size,
                              hipStream_t stream) {
  const float* x  = (const float*)d_in[0];
  const float* w1 = (const float*)d_in[1];
  const float* w2 = (const float*)d_in[2];
  const float* w3 = (const float*)d_in[3];
  float* wnorm = (float*)d_ws;
  float* xnorm = wnorm + 5376;
  unsigned long long* best = (unsigned long long*)((char*)d_ws + WS_BEST_OFF);

  hipMemsetAsync(best, 0xFF, 24576 * sizeof(unsigned long long), stream);
  norms_kernel<<<3392, 256, 0, stream>>>(x, w1, w2, w3, wnorm, xnorm);
  dist_kernel<<<dim3(84, 128), 256, 0, stream>>>(x, w1, w2, w3, wnorm, xnorm, best);
  finalize_kernel<<<6144, 256, 0, stream>>>(x, w1, w2, w3, best, (float*)d_out);
}

// Round 2
// 164.390 us; speedup vs baseline: 2.2491x; 2.2491x over previous
//
#include <hip/hip_runtime.h>
#include <hip/hip_fp16.h>
#include <stdint.h>

#define DIM 256
#define KE  768
#define NW  5376

typedef _Float16 half8 __attribute__((ext_vector_type(8)));
typedef float floatx4 __attribute__((ext_vector_type(4)));

// Workspace layout (bytes):
//   Xe    : 8192*768 ushort @ 0          (12,582,912)  [xh | xh | xl*2^11]
//   We    : 5376*768 ushort @ 12582912   ( 8,257,536)  [wh | wl*2^11 | wh]
//   wnorm : 5376 float      @ 20840448
//   xnorm : 8192 float      @ 20861952
//   best  : 24576 u64       @ 20894720   (level*8192+row) packed (d2<<32)|idx
#define WS_WE_OFF    12582912
#define WS_WNORM_OFF 20840448
#define WS_XNORM_OFF 20861952
#define WS_BEST_OFF  20894720

// One wave per row: fp32 norm + fp16 hi/lo split into the expanded layouts.
__global__ __launch_bounds__(256) void conv_kernel(
    const float* __restrict__ x, const float* __restrict__ w1,
    const float* __restrict__ w2, const float* __restrict__ w3,
    ushort* __restrict__ Xe, ushort* __restrict__ We,
    float* __restrict__ wnorm, float* __restrict__ xnorm) {
  int task = blockIdx.x * 4 + (threadIdx.x >> 6);
  int lane = threadIdx.x & 63;
  const float* src; ushort* dst; float* ndst; int isx;
  if (task < 8192) {
    src = x + (size_t)task * DIM; dst = Xe + (size_t)task * KE;
    ndst = xnorm + task; isx = 1;
  } else {
    int wi = task - 8192;
    if (wi < 256)       src = w1 + (size_t)wi * DIM;
    else if (wi < 1280) src = w2 + (size_t)(wi - 256) * DIM;
    else                src = w3 + (size_t)(wi - 1280) * DIM;
    dst = We + (size_t)wi * KE; ndst = wnorm + wi; isx = 0;
  }
  float4 v = *(const float4*)(src + lane * 4);
  float fv[4] = {v.x, v.y, v.z, v.w};
  float s = fv[0]*fv[0] + fv[1]*fv[1] + fv[2]*fv[2] + fv[3]*fv[3];
  #pragma unroll
  for (int o = 32; o > 0; o >>= 1) s += __shfl_xor(s, o);
  if (lane == 0) *ndst = s;

  ushort h[4], l[4];
  #pragma unroll
  for (int e = 0; e < 4; ++e) {
    __half hh = __float2half(fv[e]);
    float hf = __half2float(hh);
    __half ll = __float2half((fv[e] - hf) * 2048.0f);  // scaled lo: no denorms
    h[e] = __half_as_ushort(hh);
    l[e] = __half_as_ushort(ll);
  }
  ushort4 h4 = make_ushort4(h[0], h[1], h[2], h[3]);
  ushort4 l4 = make_ushort4(l[0], l[1], l[2], l[3]);
  if (isx) {  // [xh | xh | xl2]
    *(ushort4*)(dst + lane * 4)        = h4;
    *(ushort4*)(dst + 256 + lane * 4)  = h4;
    *(ushort4*)(dst + 512 + lane * 4)  = l4;
  } else {    // [wh | wl2 | wh]
    *(ushort4*)(dst + lane * 4)        = h4;
    *(ushort4*)(dst + 256 + lane * 4)  = l4;
    *(ushort4*)(dst + 512 + lane * 4)  = h4;
  }
}

// 128x128 tile MFMA GEMM over K=768 with fused per-row argmin.
// grid.x = 42 col-blocks (2 | 8 | 32 per level), grid.y = 64 row-blocks.
__global__ __launch_bounds__(256) void gemm_kernel(
    const ushort* __restrict__ Xe, const ushort* __restrict__ We,
    const float* __restrict__ xnorm, const float* __restrict__ wnorm,
    unsigned long long* __restrict__ best) {
  __shared__ __align__(16) ushort As[128 * 64];  // 16KB, XOR-swizzled chunks
  __shared__ __align__(16) ushort Bs[128 * 64];
  __shared__ unsigned long long red[2][128];

  const int cb = blockIdx.x;
  const int r0 = blockIdx.y * 128;
  const int n0 = cb * 128;
  int level, lbase;
  if (cb < 2)       { level = 0; lbase = 0; }
  else if (cb < 10) { level = 1; lbase = 256; }
  else              { level = 2; lbase = 1280; }

  const int t = threadIdx.x;
  const int w = t >> 6;
  const int lane = t & 63;
  const int ln = lane & 15, q = lane >> 4;
  const int wm = (w >> 1) * 64, wn = (w & 1) * 64;

  floatx4 acc[4][4];
  #pragma unroll
  for (int i = 0; i < 4; ++i)
    #pragma unroll
    for (int j = 0; j < 4; ++j) acc[i][j] = (floatx4)0.0f;

  for (int k0 = 0; k0 < KE; k0 += 64) {
    if (k0 == 256) {  // hh phase done: scale so cross terms (pre-scaled 2^11) match
      #pragma unroll
      for (int i = 0; i < 4; ++i)
        #pragma unroll
        for (int j = 0; j < 4; ++j) acc[i][j] *= 2048.0f;
    }
    // Stage A and B tiles: 1024 16B-chunks each; chunk p holds global
    // (row m = p>>3, colchunk c = (p&7)^(m&7)) -> conflict-free frag reads.
    #pragma unroll
    for (int it = 0; it < 4; ++it) {
      int p = it * 256 + t;
      int m = p >> 3;
      int c = (p & 7) ^ (m & 7);
      const ushort* ga = Xe + (size_t)(r0 + m) * KE + k0 + c * 8;
      const ushort* gb = We + (size_t)(n0 + m) * KE + k0 + c * 8;
      int lbase_chunks = it * 256 + (t & 192);  // wave-uniform
      __builtin_amdgcn_global_load_lds(
          (const __attribute__((address_space(1))) void*)ga,
          (__attribute__((address_space(3))) void*)(As + lbase_chunks * 8), 16, 0, 0);
      __builtin_amdgcn_global_load_lds(
          (const __attribute__((address_space(1))) void*)gb,
          (__attribute__((address_space(3))) void*)(Bs + lbase_chunks * 8), 16, 0, 0);
    }
    __syncthreads();
    #pragma unroll
    for (int s = 0; s < 2; ++s) {
      half8 a[4], b[4];
      #pragma unroll
      for (int mt = 0; mt < 4; ++mt) {
        int m = wm + mt * 16 + ln;
        int pos = m * 8 + ((s * 4 + q) ^ (m & 7));
        a[mt] = *(const half8*)&As[pos * 8];
      }
      #pragma unroll
      for (int nt = 0; nt < 4; ++nt) {
        int n = wn + nt * 16 + ln;
        int pos = n * 8 + ((s * 4 + q) ^ (n & 7));
        b[nt] = *(const half8*)&Bs[pos * 8];
      }
      #pragma unroll
      for (int mt = 0; mt < 4; ++mt)
        #pragma unroll
        for (int nt = 0; nt < 4; ++nt)
          acc[mt][nt] = __builtin_amdgcn_mfma_f32_16x16x32_f16(
              a[mt], b[nt], acc[mt][nt], 0, 0, 0);
    }
    __syncthreads();
  }

  // acc = 2^11 * dot. d2 = xn + wn - 2*dot = xn + wn - acc * 2^-10.
  float wnv[4];
  #pragma unroll
  for (int nt = 0; nt < 4; ++nt) wnv[nt] = wnorm[n0 + wn + nt * 16 + ln];

  #pragma unroll
  for (int mt = 0; mt < 4; ++mt) {
    #pragma unroll
    for (int r = 0; r < 4; ++r) {
      int rowl = wm + mt * 16 + q * 4 + r;
      float xnv = xnorm[r0 + rowl];
      unsigned long long bp = ~0ull;
      #pragma unroll
      for (int nt = 0; nt < 4; ++nt) {
        float d2 = fmaxf(xnv + wnv[nt] - acc[mt][nt][r] * 0.0009765625f, 0.0f);
        unsigned col = (unsigned)(n0 + wn + nt * 16 + ln - lbase);
        unsigned long long p =
            ((unsigned long long)__float_as_uint(d2) << 32) | col;
        bp = (p < bp) ? p : bp;
      }
      #pragma unroll
      for (int off = 1; off < 16; off <<= 1) {
        unsigned long long o = __shfl_xor(bp, off);
        bp = (o < bp) ? o : bp;
      }
      if (ln == 0) red[w & 1][rowl] = bp;
    }
  }
  __syncthreads();
  if (t < 128) {
    unsigned long long a = red[0][t], b = red[1][t];
    unsigned long long m = (a < b) ? a : b;
    atomicMin(&best[level * 8192 + r0 + t], m);
  }
}

// One wave per (level,row): coords + exact fp32 quantization error.
__global__ __launch_bounds__(256) void finalize_kernel(
    const float* __restrict__ x, const float* __restrict__ w1,
    const float* __restrict__ w2, const float* __restrict__ w3,
    const unsigned long long* __restrict__ best, float* __restrict__ out) {
  int task = blockIdx.x * 4 + (threadIdx.x >> 6);
  int lane = threadIdx.x & 63;
  int level = task >> 13;
  int row = task & 8191;
  const float* w; unsigned side;
  if (level == 0)      { w = w1; side = 16; }
  else if (level == 1) { w = w2; side = 32; }
  else                 { w = w3; side = 64; }
  unsigned idx = (unsigned)(best[level * 8192 + row] & 0xFFFFFFFFull);
  float4 xv = *(const float4*)(x + (size_t)row * DIM + lane * 4);
  float4 wv = *(const float4*)(w + (size_t)idx * DIM + lane * 4);
  float dx = xv.x - wv.x, dy = xv.y - wv.y, dz = xv.z - wv.z, dw = xv.w - wv.w;
  float s = dx * dx + dy * dy + dz * dz + dw * dw;
  #pragma unroll
  for (int o = 32; o > 0; o >>= 1) s += __shfl_xor(s, o);
  if (lane == 0) {
    out[level * 16384 + row * 2 + 0] = (float)(idx / side);
    out[level * 16384 + row * 2 + 1] = (float)(idx % side);
    out[49152 + level * 8192 + row] = sqrtf(s);
  }
}

extern "C" void kernel_launch(void* const* d_in, const int* in_sizes, int n_in,
                              void* d_out, int out_size, void* d_ws, size_t ws_size,
                              hipStream_t stream) {
  const float* x  = (const float*)d_in[0];
  const float* w1 = (const float*)d_in[1];
  const float* w2 = (const float*)d_in[2];
  const float* w3 = (const float*)d_in[3];
  ushort* Xe = (ushort*)d_ws;
  ushort* We = (ushort*)((char*)d_ws + WS_WE_OFF);
  float* wnorm = (float*)((char*)d_ws + WS_WNORM_OFF);
  float* xnorm = (float*)((char*)d_ws + WS_XNORM_OFF);
  unsigned long long* best = (unsigned long long*)((char*)d_ws + WS_BEST_OFF);

  hipMemsetAsync(best, 0xFF, 24576 * sizeof(unsigned long long), stream);
  conv_kernel<<<3392, 256, 0, stream>>>(x, w1, w2, w3, Xe, We, wnorm, xnorm);
  gemm_kernel<<<dim3(42, 64), 256, 0, stream>>>(Xe, We, xnorm, wnorm, best);
  finalize_kernel<<<6144, 256, 0, stream>>>(x, w1, w2, w3, best, (float*)d_out);
}